// Round 5
// baseline (272.155 us; speedup 1.0000x reference)
//
#include <hip/hip_runtime.h>
#include <hip/hip_bf16.h>
#include <math.h>

#define BB 4
#define SS 512
#define DD 768
#define II 64
#define LL 2
#define HH 12
#define FF 3072

using short8 = __attribute__((ext_vector_type(8))) short;
using f32x4  = __attribute__((ext_vector_type(4))) float;

__device__ __forceinline__ unsigned short f2bf(float x) {
  return __builtin_bit_cast(unsigned short, __float2bfloat16(x));
}

__device__ __forceinline__ void gload_lds16(const void* g, void* l) {
  __builtin_amdgcn_global_load_lds((const __attribute__((address_space(1))) unsigned int*)g,
                                   (__attribute__((address_space(3))) unsigned int*)l, 16, 0, 0);
}

// ---------------- cast hs0/hs1 to bf16 ----------------
__global__ __launch_bounds__(256) void cast2_kernel(const float* __restrict__ a, const float* __restrict__ b,
                                                    unsigned short* __restrict__ oa, unsigned short* __restrict__ ob) {
  int idx = blockIdx.x * 256 + threadIdx.x;
  float4 va = ((const float4*)a)[idx];
  float4 vb = ((const float4*)b)[idx];
  union { unsigned short u[4]; uint2 v; } pa, pb;
  pa.u[0] = f2bf(va.x); pa.u[1] = f2bf(va.y); pa.u[2] = f2bf(va.z); pa.u[3] = f2bf(va.w);
  pb.u[0] = f2bf(vb.x); pb.u[1] = f2bf(vb.y); pb.u[2] = f2bf(vb.z); pb.u[3] = f2bf(vb.w);
  ((uint2*)oa)[idx] = pa.v;
  ((uint2*)ob)[idx] = pb.v;
}

// ---------------- unified transpose+cast for all weights ----------------
// z<8: square weights [Wq,Wk,Wv,Wo]x[L]; z=8,9: W1[l]; z=10,11: W2[l]
struct TC { const float* s[6]; };

__global__ __launch_bounds__(256) void tcast_all(TC src, unsigned short* __restrict__ WT4,
                                                 unsigned short* __restrict__ W1T,
                                                 unsigned short* __restrict__ W2T) {
  __shared__ float tile[32][33];
  int z = blockIdx.z;
  const float* Ws; unsigned short* WTs; int K, N, n0, k0;
  if (z < 8) {
    if (blockIdx.x >= 24) return;
    int widx = z >> 1, l = z & 1;
    Ws = src.s[widx] + (size_t)l * DD * DD;
    WTs = WT4 + ((size_t)widx * 2 + l) * DD * DD;
    K = DD; N = DD; n0 = blockIdx.x * 32; k0 = blockIdx.y * 32;
  } else if (z < 10) {
    int l = z - 8;
    Ws = src.s[4] + (size_t)l * DD * FF;
    WTs = W1T + (size_t)l * FF * DD;
    K = DD; N = FF; n0 = blockIdx.x * 32; k0 = blockIdx.y * 32;
  } else {
    int l = z - 10;
    Ws = src.s[5] + (size_t)l * FF * DD;
    WTs = W2T + (size_t)l * DD * FF;
    K = FF; N = DD; n0 = blockIdx.y * 32; k0 = blockIdx.x * 32;
  }
  int tx = threadIdx.x, ty = threadIdx.y;  // (32,8)
  #pragma unroll
  for (int r = 0; r < 4; ++r) tile[ty + 8 * r][tx] = Ws[(size_t)(k0 + ty + 8 * r) * N + (n0 + tx)];
  __syncthreads();
  #pragma unroll
  for (int r = 0; r < 4; ++r) WTs[(size_t)(n0 + ty + 8 * r) * K + (k0 + tx)] = f2bf(tile[tx][ty + 8 * r]);
}

// ---------------- masked max pooling + zero_indic + bit-packed inclusion mask ----------------
__global__ __launch_bounds__(256) void pool_kernel(const float* __restrict__ hs0, const int* __restrict__ mask,
                                                   int* __restrict__ zi, float* __restrict__ qf,
                                                   unsigned short* __restrict__ qb,
                                                   unsigned long long* __restrict__ pmask) {
  __shared__ float eadd[SS];
  int bi = blockIdx.x;  // b*II + i
  int b = bi >> 6, dz = blockIdx.y, t = threadIdx.x, w = t >> 6;
  const int* mrow = mask + (size_t)bi * SS;
  int m0v = mrow[t], m1v = mrow[t + 256];
  eadd[t] = m0v ? -__builtin_inff() : 0.0f;
  eadd[t + 256] = m1v ? -__builtin_inff() : 0.0f;
  int incl = (m0v == 0) | (m1v == 0);
  int any = __syncthreads_or(incl);
  int z = !any;
  if (dz == 0) {
    unsigned long long w0 = __ballot(z || (m0v == 0));
    unsigned long long w1 = __ballot(z || (m1v == 0));
    if ((t & 63) == 0) {
      pmask[bi * 8 + w] = w0;
      pmask[bi * 8 + 4 + w] = w1;
      if (t == 0) zi[bi] = z;
    }
  }
  const float* hb = hs0 + (size_t)b * SS * DD + dz * 256 + t;
  float m[8];
  #pragma unroll
  for (int j = 0; j < 8; ++j) m[j] = -3.4e38f;
  for (int s0 = 0; s0 < SS; s0 += 8) {
    #pragma unroll
    for (int j = 0; j < 8; ++j)
      m[j] = fmaxf(m[j], hb[(size_t)(s0 + j) * DD] + eadd[s0 + j]);
  }
  float mm = fmaxf(fmaxf(fmaxf(m[0], m[1]), fmaxf(m[2], m[3])),
                   fmaxf(fmaxf(m[4], m[5]), fmaxf(m[6], m[7])));
  size_t o = (size_t)bi * DD + dz * 256 + t;
  qf[o] = mm;
  qb[o] = f2bf(mm);
}

// ---------------- NT GEMM 128x128 (4 problems via z; odd z = transposed block map) ----------------
struct GB { const unsigned short* A; const unsigned short* Bt; const float* bias; void* C;
            int M; int N; int rowbias; };

template <int GELU, int OUTBF>
__global__ __launch_bounds__(256) void gemm_nt(GB g0, GB g1, GB g2, GB g3, int K) {
  __shared__ unsigned short Al[128 * 64];
  __shared__ unsigned short Bl[128 * 64];
  GB g = (blockIdx.z == 0) ? g0 : (blockIdx.z == 1) ? g1 : (blockIdx.z == 2) ? g2 : g3;
  int bm = blockIdx.x, bn = blockIdx.y;
  if (blockIdx.z & 1) { bm = blockIdx.y; bn = blockIdx.x; }
  if (bm * 128 >= g.M) return;
  int t = threadIdx.x, w = t >> 6, lane = t & 63;
  int hi = lane >> 4, lo = lane & 15;
  int wr = w >> 1, wc = w & 1;
  f32x4 acc[4][4] = {};
  const char* Abase = (const char*)g.A + (size_t)(bm * 128) * (size_t)K * 2;
  const char* Bbase = (const char*)g.Bt + (size_t)(bn * 128) * (size_t)K * 2;
  int rowbytes = K * 2;
  int KT = K >> 6;
  for (int kt = 0; kt < KT; ++kt) {
    int k0b = kt * 128;
    #pragma unroll
    for (int c = 0; c < 4; ++c) {
      int base = (c * 4 + w) << 10;
      int o = base + lane * 16;
      int row = o >> 7, cb = o & 127;
      int scb = cb ^ ((row & 7) << 4);
      gload_lds16(Abase + (size_t)row * rowbytes + (k0b + scb), (char*)Al + base);
      gload_lds16(Bbase + (size_t)row * rowbytes + (k0b + scb), (char*)Bl + base);
    }
    __syncthreads();
    #pragma unroll
    for (int kk = 0; kk < 2; ++kk) {
      short8 av[4], bv_[4];
      #pragma unroll
      for (int mi = 0; mi < 4; ++mi) {
        int r = wr * 64 + mi * 16 + lo;
        av[mi] = *(const short8*)((const char*)Al + r * 128 + ((kk * 64 + hi * 16) ^ ((r & 7) << 4)));
      }
      #pragma unroll
      for (int ni = 0; ni < 4; ++ni) {
        int r = wc * 64 + ni * 16 + lo;
        bv_[ni] = *(const short8*)((const char*)Bl + r * 128 + ((kk * 64 + hi * 16) ^ ((r & 7) << 4)));
      }
      #pragma unroll
      for (int mi = 0; mi < 4; ++mi)
        #pragma unroll
        for (int ni = 0; ni < 4; ++ni)
          acc[mi][ni] = __builtin_amdgcn_mfma_f32_16x16x32_bf16(av[mi], bv_[ni], acc[mi][ni], 0, 0, 0);
    }
    __syncthreads();
  }
  int mbase = bm * 128 + wr * 64;
  int nbase = bn * 128 + wc * 64;
  #pragma unroll
  for (int mi = 0; mi < 4; ++mi)
    #pragma unroll
    for (int ni = 0; ni < 4; ++ni)
      #pragma unroll
      for (int r = 0; r < 4; ++r) {
        int gm = mbase + mi * 16 + hi * 4 + r;
        int gn = nbase + ni * 16 + lo;
        float v = acc[mi][ni][r] + (g.rowbias ? g.bias[gm] : g.bias[gn]);
        if (GELU) v = 0.5f * v * (1.0f + erff(v * 0.70710678118654752f));
        if (OUTBF) ((unsigned short*)g.C)[(size_t)gm * g.N + gn] = f2bf(v);
        else       ((float*)g.C)[(size_t)gm * g.N + gn] = v;
      }
}

// ---------------- register-direct NT GEMM 64x64 (no LDS, no barriers) ----------------
// For small-M GEMMs whose operands are L2/L3-resident. Each lane loads its MFMA
// fragments straight from global (16B contiguous); unroll-4 keeps 16 loads in flight.
template <int GELU, int OUTBF>
__global__ __launch_bounds__(256) void gemm_reg(GB g, int K) {
  int bm = blockIdx.x, bn = blockIdx.y;
  int t = threadIdx.x, w = t >> 6, lane = t & 63;
  int hi = lane >> 4, lo = lane & 15;
  int wr = w >> 1, wc = w & 1;
  size_t rb = (size_t)K * 2;
  const char* A0 = (const char*)g.A + (size_t)(bm * 64 + wr * 32 + lo) * rb + hi * 16;
  const char* A1 = A0 + 16 * rb;
  const char* B0 = (const char*)g.Bt + (size_t)(bn * 64 + wc * 32 + lo) * rb + hi * 16;
  const char* B1 = B0 + 16 * rb;
  f32x4 acc[2][2] = {};
  int KB = K * 2;
  #pragma unroll 4
  for (int ks = 0; ks < KB; ks += 64) {
    short8 a0 = *(const short8*)(A0 + ks);
    short8 a1 = *(const short8*)(A1 + ks);
    short8 b0 = *(const short8*)(B0 + ks);
    short8 b1 = *(const short8*)(B1 + ks);
    acc[0][0] = __builtin_amdgcn_mfma_f32_16x16x32_bf16(a0, b0, acc[0][0], 0, 0, 0);
    acc[0][1] = __builtin_amdgcn_mfma_f32_16x16x32_bf16(a0, b1, acc[0][1], 0, 0, 0);
    acc[1][0] = __builtin_amdgcn_mfma_f32_16x16x32_bf16(a1, b0, acc[1][0], 0, 0, 0);
    acc[1][1] = __builtin_amdgcn_mfma_f32_16x16x32_bf16(a1, b1, acc[1][1], 0, 0, 0);
  }
  int mbase = bm * 64 + wr * 32;
  int nbase = bn * 64 + wc * 32;
  #pragma unroll
  for (int mi = 0; mi < 2; ++mi)
    #pragma unroll
    for (int ni = 0; ni < 2; ++ni)
      #pragma unroll
      for (int r = 0; r < 4; ++r) {
        int gm = mbase + mi * 16 + hi * 4 + r;
        int gn = nbase + ni * 16 + lo;
        float v = acc[mi][ni][r] + (g.rowbias ? g.bias[gm] : g.bias[gn]);
        if (GELU) v = 0.5f * v * (1.0f + erff(v * 0.70710678118654752f));
        if (OUTBF) ((unsigned short*)g.C)[(size_t)gm * g.N + gn] = f2bf(v);
        else       ((float*)g.C)[(size_t)gm * g.N + gn] = v;
      }
}

// ---------------- fused attention per (b,h): Qproj + QK^T + softmax + PV ----------------
// LDS: Qd 8K | KP 64K (K tiles, later P) | Vd 64K | pm 4K | red 1K | red2 1K | rnv 256B
#define ATTN_LDS 145664
__global__ __launch_bounds__(256) void attn_kernel(
    const unsigned short* __restrict__ qbuf, const unsigned short* __restrict__ WqTl,
    const float* __restrict__ bql, const unsigned short* __restrict__ khb,
    const unsigned short* __restrict__ vTall, const unsigned long long* __restrict__ pmask,
    unsigned short* __restrict__ ctx) {
  extern __shared__ char lds[];
  char* Qd = lds;
  char* KP = lds + 8192;
  char* Vd = lds + 8192 + 65536;
  unsigned long long* pm = (unsigned long long*)(lds + 139264);
  float* red  = (float*)(lds + 143360);
  float* red2 = (float*)(lds + 144384);
  float* rnv  = (float*)(lds + 145408);
  int bh = blockIdx.x;
  int b = bh / HH, h = bh - b * HH;
  int t = threadIdx.x, w = t >> 6, l = t & 63, hi = l >> 4, lo = l & 15;
  int o16 = l * 16, ro = o16 >> 7, cb = o16 & 127;

  // issue V staging (vT rows h*64.., cols b*512..; row stride 4096 B)
  const char* vsrc = (const char*)vTall + (size_t)(h * 64) * 4096 + (size_t)b * 1024;
  #pragma unroll
  for (int rr = 0; rr < 16; ++rr) {
    int rv = w * 16 + rr;
    gload_lds16(vsrc + (size_t)rv * 4096 + ((l * 16) ^ ((rv & 7) << 4)), Vd + rv * 1024);
  }
  // pm staging (64 rows x 64B)
  if (w == 0) {
    const char* psrc = (const char*)pmask + (size_t)b * 4096;
    #pragma unroll
    for (int c = 0; c < 4; ++c) gload_lds16(psrc + c * 1024 + l * 16, (char*)pm + c * 1024);
  }

  // ---- Q projection (pipelined, staging in KP region: A0/B0/A1/B1 8K each) ----
  const char* Aq = (const char*)qbuf + (size_t)(b * II) * 1536;
  const char* Bq = (const char*)WqTl + (size_t)(h * 64) * 1536;
  f32x4 qacc[4] = {};
  #pragma unroll
  for (int cc = 0; cc < 2; ++cc) {
    int ch = w * 2 + cc, row = ch * 8 + ro;
    int scb = cb ^ ((row & 7) << 4);
    gload_lds16(Aq + (size_t)row * 1536 + scb, KP + ch * 1024);
    gload_lds16(Bq + (size_t)row * 1536 + scb, KP + 8192 + ch * 1024);
  }
  __syncthreads();
  for (int kt = 0; kt < 12; ++kt) {
    int cur = (kt & 1) * 16384;
    if (kt < 11) {
      int nxt = ((kt + 1) & 1) * 16384;
      int kb = (kt + 1) * 128;
      #pragma unroll
      for (int cc = 0; cc < 2; ++cc) {
        int ch = w * 2 + cc, row = ch * 8 + ro;
        int scb = kb + (cb ^ ((row & 7) << 4));
        gload_lds16(Aq + (size_t)row * 1536 + scb, KP + nxt + ch * 1024);
        gload_lds16(Bq + (size_t)row * 1536 + scb, KP + nxt + 8192 + ch * 1024);
      }
    }
    #pragma unroll
    for (int kk = 0; kk < 2; ++kk) {
      int ra = w * 16 + lo;
      short8 av = *(const short8*)(KP + cur + ra * 128 + ((kk * 64 + hi * 16) ^ ((ra & 7) << 4)));
      #pragma unroll
      for (int ni = 0; ni < 4; ++ni) {
        int rb2 = ni * 16 + lo;
        short8 bv = *(const short8*)(KP + cur + 8192 + rb2 * 128 + ((kk * 64 + hi * 16) ^ ((rb2 & 7) << 4)));
        qacc[ni] = __builtin_amdgcn_mfma_f32_16x16x32_bf16(av, bv, qacc[ni], 0, 0, 0);
      }
    }
    __syncthreads();
  }
  // write Q (bf16, swizzled [64][128B])
  #pragma unroll
  for (int ni = 0; ni < 4; ++ni)
    #pragma unroll
    for (int r = 0; r < 4; ++r) {
      int row = w * 16 + hi * 4 + r, col = ni * 16 + lo;
      float v = qacc[ni][r] + bql[h * 64 + col];
      *(unsigned short*)(Qd + row * 128 + ((col * 2) ^ ((row & 7) << 4))) = f2bf(v);
    }
  // ---- stage K (512 rows x 128B) ----
  const char* Ks = (const char*)khb + (size_t)(b * SS) * 1536 + h * 128;
  #pragma unroll
  for (int cc = 0; cc < 16; ++cc) {
    int ch = w * 16 + cc, row = ch * 8 + ro;
    int scb = cb ^ ((row & 7) << 4);
    gload_lds16(Ks + (size_t)row * 1536 + scb, KP + ch * 1024);
  }
  __syncthreads();

  // ---- QK^T: wave w owns cols w*128..w*128+127, all 64 rows ----
  f32x4 acc[4][8] = {};
  #pragma unroll
  for (int kk = 0; kk < 2; ++kk) {
    short8 av[4];
    #pragma unroll
    for (int mi = 0; mi < 4; ++mi) {
      int ra = mi * 16 + lo;
      av[mi] = *(const short8*)(Qd + ra * 128 + ((kk * 64 + hi * 16) ^ ((ra & 7) << 4)));
    }
    #pragma unroll
    for (int ni = 0; ni < 8; ++ni) {
      int rk = w * 128 + ni * 16 + lo;
      short8 bv = *(const short8*)(KP + rk * 128 + ((kk * 64 + hi * 16) ^ ((rk & 7) << 4)));
      #pragma unroll
      for (int mi = 0; mi < 4; ++mi)
        acc[mi][ni] = __builtin_amdgcn_mfma_f32_16x16x32_bf16(av[mi], bv, acc[mi][ni], 0, 0, 0);
    }
  }
  // ---- row max (raw scores; softmax is shift-invariant) ----
  #pragma unroll
  for (int mi = 0; mi < 4; ++mi)
    #pragma unroll
    for (int r = 0; r < 4; ++r) {
      float m = acc[mi][0][r];
      #pragma unroll
      for (int ni = 1; ni < 8; ++ni) m = fmaxf(m, acc[mi][ni][r]);
      #pragma unroll
      for (int xm = 1; xm <= 8; xm <<= 1) m = fmaxf(m, __shfl_xor(m, xm));
      if (lo == 0) red[(mi * 16 + hi * 4 + r) * 4 + w] = m;
    }
  __syncthreads();
  // ---- exp * inclusion + sum; write P (unnormalized bf16) over K region ----
  #pragma unroll
  for (int mi = 0; mi < 4; ++mi)
    #pragma unroll
    for (int r = 0; r < 4; ++r) {
      int row = mi * 16 + hi * 4 + r;
      float4 rm4 = *(const float4*)&red[row * 4];
      float gm = fmaxf(fmaxf(rm4.x, rm4.y), fmaxf(rm4.z, rm4.w));
      unsigned long long w0 = pm[row * 8 + w * 2 + 0];
      unsigned long long w1 = pm[row * 8 + w * 2 + 1];
      float s = 0.f;
      #pragma unroll
      for (int ni = 0; ni < 8; ++ni) {
        int sl = ni * 16 + lo;
        unsigned long long word = (sl < 64) ? w0 : w1;
        float in = ((word >> (sl & 63)) & 1ull) ? 1.0f : 0.0f;
        float e = __expf((acc[mi][ni][r] - gm) * 0.125f) * in;
        s += e;
        int sbyte = w * 256 + ni * 32 + lo * 2;
        *(unsigned short*)(KP + row * 1024 + (sbyte ^ ((row & 7) << 4))) = f2bf(e);
      }
      #pragma unroll
      for (int xm = 1; xm <= 8; xm <<= 1) s += __shfl_xor(s, xm);
      if (lo == 0) red2[row * 4 + w] = s;
    }
  __syncthreads();
  if (w == 0 && lo == 0) {
    #pragma unroll
    for (int mi = 0; mi < 4; ++mi)
      #pragma unroll
      for (int r = 0; r < 4; ++r) {
        int row = mi * 16 + hi * 4 + r;
        float4 s4 = *(const float4*)&red2[row * 4];
        rnv[row] = 1.0f / ((s4.x + s4.y) + (s4.z + s4.w));
      }
  }
  __syncthreads();
  // ---- PV: wave w owns output cols w*16..w*16+15, rows all 64, K=512 ----
  f32x4 pacc[4] = {};
  for (int kk = 0; kk < 16; ++kk) {
    int rv = w * 16 + lo;
    short8 bv = *(const short8*)(Vd + rv * 1024 + ((kk * 64 + hi * 16) ^ ((rv & 7) << 4)));
    #pragma unroll
    for (int mi = 0; mi < 4; ++mi) {
      int ra = mi * 16 + lo;
      short8 av = *(const short8*)(KP + ra * 1024 + ((kk * 64 + hi * 16) ^ ((ra & 7) << 4)));
      pacc[mi] = __builtin_amdgcn_mfma_f32_16x16x32_bf16(av, bv, pacc[mi], 0, 0, 0);
    }
  }
  #pragma unroll
  for (int mi = 0; mi < 4; ++mi)
    #pragma unroll
    for (int r = 0; r < 4; ++r) {
      int row = mi * 16 + hi * 4 + r;
      ctx[(size_t)(b * II + row) * DD + h * 64 + w * 16 + lo] = f2bf(pacc[mi][r] * rnv[row]);
    }
}

// ---------------- residual + LayerNorm (FINAL=1 fuses zero-context substitution + d_out) ----------------
template <int FINAL>
__global__ __launch_bounds__(256) void ln_kernel(const float* __restrict__ x, const float* __restrict__ y,
                                                 const float* __restrict__ g, const float* __restrict__ bb,
                                                 float* __restrict__ qf, unsigned short* __restrict__ qb,
                                                 const int* __restrict__ zi, const float* __restrict__ zc,
                                                 float* __restrict__ out) {
  __shared__ float r1[4], r2[4];
  int r = blockIdx.x, t = threadIdx.x;
  size_t o = (size_t)r * DD;
  float v0 = x[o + t] + y[o + t];
  float v1 = x[o + t + 256] + y[o + t + 256];
  float v2 = x[o + t + 512] + y[o + t + 512];
  float s = v0 + v1 + v2, ss = v0 * v0 + v1 * v1 + v2 * v2;
  #pragma unroll
  for (int o2 = 32; o2; o2 >>= 1) { s += __shfl_xor(s, o2); ss += __shfl_xor(ss, o2); }
  if ((t & 63) == 0) { r1[t >> 6] = s; r2[t >> 6] = ss; }
  __syncthreads();
  s = r1[0] + r1[1] + r1[2] + r1[3];
  ss = r2[0] + r2[1] + r2[2] + r2[3];
  float mean = s * (1.0f / DD);
  float var = ss * (1.0f / DD) - mean * mean;
  float inv = rsqrtf(var + 1e-12f);
  float w0 = (v0 - mean) * inv * g[t] + bb[t];
  float w1 = (v1 - mean) * inv * g[t + 256] + bb[t + 256];
  float w2 = (v2 - mean) * inv * g[t + 512] + bb[t + 512];
  if (FINAL) {
    int z = zi[r];
    out[o + t] = z ? zc[t] : w0;
    out[o + t + 256] = z ? zc[t + 256] : w1;
    out[o + t + 512] = z ? zc[t + 512] : w2;
  } else {
    qf[o + t] = w0; qf[o + t + 256] = w1; qf[o + t + 512] = w2;
    qb[o + t] = f2bf(w0); qb[o + t + 256] = f2bf(w1); qb[o + t + 512] = f2bf(w2);
  }
}

extern "C" void kernel_launch(void* const* d_in, const int* in_sizes, int n_in,
                              void* d_out, int out_size, void* d_ws, size_t ws_size,
                              hipStream_t stream) {
  (void)in_sizes; (void)n_in; (void)out_size; (void)ws_size;
  const float* hs0 = (const float*)d_in[0];
  const float* hs1 = (const float*)d_in[1];
  const float* Wq  = (const float*)d_in[3];
  const float* bq  = (const float*)d_in[4];
  const float* Wk  = (const float*)d_in[5];
  const float* bk  = (const float*)d_in[6];
  const float* Wv  = (const float*)d_in[7];
  const float* bv  = (const float*)d_in[8];
  const float* Wo  = (const float*)d_in[9];
  const float* bo  = (const float*)d_in[10];
  const float* ln1g = (const float*)d_in[11];
  const float* ln1b = (const float*)d_in[12];
  const float* W1  = (const float*)d_in[13];
  const float* b1  = (const float*)d_in[14];
  const float* W2  = (const float*)d_in[15];
  const float* b2  = (const float*)d_in[16];
  const float* ln2g = (const float*)d_in[17];
  const float* ln2b = (const float*)d_in[18];
  const float* zc  = (const float*)d_in[19];
  const int*   mask = (const int*)d_in[20];

  char* ws = (char*)d_ws;
  size_t off = 0;
  auto alloc = [&](size_t bytes) { size_t o = off; off += (bytes + 255) & ~(size_t)255; return o; };

  unsigned short* WT4 = (unsigned short*)(ws + alloc((size_t)4 * LL * DD * DD * 2));
  unsigned short* W1T = (unsigned short*)(ws + alloc((size_t)LL * FF * DD * 2));
  unsigned short* W2T = (unsigned short*)(ws + alloc((size_t)LL * DD * FF * 2));
  unsigned short* hsb = (unsigned short*)(ws + alloc((size_t)2 * BB * SS * DD * 2));
  float*          qf  = (float*)(ws + alloc((size_t)BB * II * DD * 4));
  unsigned short* qb  = (unsigned short*)(ws + alloc((size_t)BB * II * DD * 2));
  unsigned short* khb = (unsigned short*)(ws + alloc((size_t)LL * BB * SS * DD * 2));
  unsigned short* vTall = (unsigned short*)(ws + alloc((size_t)LL * DD * BB * SS * 2));  // [l][768][2048]
  unsigned short* ctxb = (unsigned short*)(ws + alloc((size_t)BB * II * DD * 2));
  float*          att_o = (float*)(ws + alloc((size_t)BB * II * DD * 4));
  unsigned short* ffh = (unsigned short*)(ws + alloc((size_t)BB * II * FF * 2));
  float*          ffo = (float*)(ws + alloc((size_t)BB * II * DD * 4));
  unsigned long long* pmask = (unsigned long long*)(ws + alloc((size_t)BB * II * 8 * 8));
  int*            zib = (int*)(ws + alloc((size_t)BB * II * 4));

  unsigned short* WqT = WT4 + 0 * (size_t)LL * DD * DD;
  unsigned short* WkT = WT4 + 1 * (size_t)LL * DD * DD;
  unsigned short* WvT = WT4 + 2 * (size_t)LL * DD * DD;
  unsigned short* WoT = WT4 + 3 * (size_t)LL * DD * DD;

  (void)hipFuncSetAttribute((const void*)attn_kernel,
                            hipFuncAttributeMaxDynamicSharedMemorySize, ATTN_LDS);

  dim3 tb(32, 8);
  TC tc = { { Wq, Wk, Wv, Wo, W1, W2 } };
  tcast_all<<<dim3(96, 24, 12), tb, 0, stream>>>(tc, WT4, W1T, W2T);
  cast2_kernel<<<(BB * SS * DD / 4) / 256, 256, 0, stream>>>(hs0, hs1, hsb, hsb + (size_t)BB * SS * DD);
  pool_kernel<<<dim3(BB * II, 3), 256, 0, stream>>>(hs0, mask, zib, qf, qb, pmask);

  // K projections + transposed V projections for BOTH layers in one launch
  {
    const unsigned short* h0 = hsb;
    const unsigned short* h1 = hsb + (size_t)BB * SS * DD;
    unsigned short* kh0 = khb;
    unsigned short* kh1 = khb + (size_t)BB * SS * DD;
    unsigned short* vT0 = vTall;
    unsigned short* vT1 = vTall + (size_t)DD * BB * SS;
    GB gK0 = { h0, WkT, bk, kh0, BB * SS, DD, 0 };
    GB gV0 = { WvT, h0, bv, vT0, DD, BB * SS, 1 };
    GB gK1 = { h1, WkT + (size_t)DD * DD, bk + DD, kh1, BB * SS, DD, 0 };
    GB gV1 = { WvT + (size_t)DD * DD, h1, bv + DD, vT1, DD, BB * SS, 1 };
    gemm_nt<0, 1><<<dim3(16, 6, 4), 256, 0, stream>>>(gK0, gV0, gK1, gV1, DD);
  }

  for (int l = 0; l < LL; ++l) {
    const unsigned short* khl = khb + (size_t)l * BB * SS * DD;
    const unsigned short* vTl = vTall + (size_t)l * DD * BB * SS;
    // fused attention (includes Q projection)
    attn_kernel<<<dim3(BB * HH), 256, ATTN_LDS, stream>>>(
        qb, WqT + (size_t)l * DD * DD, bq + l * DD, khl, vTl, pmask, ctxb);
    // Wo projection (register-direct)
    GB gO = { ctxb, WoT + (size_t)l * DD * DD, bo + l * DD, att_o, BB * II, DD, 0 };
    gemm_reg<0, 0><<<dim3(4, 12), 256, 0, stream>>>(gO, DD);
    // LN1
    ln_kernel<0><<<BB * II, 256, 0, stream>>>(qf, att_o, ln1g + l * DD, ln1b + l * DD, qf, qb,
                                              nullptr, nullptr, nullptr);
    // FFN1 (GELU)
    GB gF1 = { qb, W1T + (size_t)l * FF * DD, b1 + l * FF, ffh, BB * II, FF, 0 };
    gemm_reg<1, 1><<<dim3(4, FF / 64), 256, 0, stream>>>(gF1, DD);
    // FFN2
    GB gF2 = { ffh, W2T + (size_t)l * DD * FF, b2 + l * DD, ffo, BB * II, DD, 0 };
    gemm_reg<0, 0><<<dim3(4, 12), 256, 0, stream>>>(gF2, FF);
    // LN2 (layer 1: fused zero-context substitution into d_out)
    if (l == 0)
      ln_kernel<0><<<BB * II, 256, 0, stream>>>(qf, ffo, ln2g + l * DD, ln2b + l * DD, qf, qb,
                                                nullptr, nullptr, nullptr);
    else
      ln_kernel<1><<<BB * II, 256, 0, stream>>>(qf, ffo, ln2g + l * DD, ln2b + l * DD, nullptr, nullptr,
                                                zib, zc, (float*)d_out);
  }
}

// Round 6
// 179.503 us; speedup vs baseline: 1.5162x; 1.5162x over previous
//
#include <hip/hip_runtime.h>
#include <hip/hip_bf16.h>
#include <math.h>

#define BB 4
#define SS 512
#define DD 768
#define II 64
#define LL 2
#define HH 12
#define FF 3072

using short8 = __attribute__((ext_vector_type(8))) short;
using f32x4  = __attribute__((ext_vector_type(4))) float;

__device__ __forceinline__ unsigned short f2bf(float x) {
  return __builtin_bit_cast(unsigned short, __float2bfloat16(x));
}

__device__ __forceinline__ void gload_lds16(const void* g, void* l) {
  __builtin_amdgcn_global_load_lds((const __attribute__((address_space(1))) unsigned int*)g,
                                   (__attribute__((address_space(3))) unsigned int*)l, 16, 0, 0);
}

// ---------------- cast hs0/hs1 to bf16 ----------------
__global__ __launch_bounds__(256) void cast2_kernel(const float* __restrict__ a, const float* __restrict__ b,
                                                    unsigned short* __restrict__ oa, unsigned short* __restrict__ ob) {
  int idx = blockIdx.x * 256 + threadIdx.x;
  float4 va = ((const float4*)a)[idx];
  float4 vb = ((const float4*)b)[idx];
  union { unsigned short u[4]; uint2 v; } pa, pb;
  pa.u[0] = f2bf(va.x); pa.u[1] = f2bf(va.y); pa.u[2] = f2bf(va.z); pa.u[3] = f2bf(va.w);
  pb.u[0] = f2bf(vb.x); pb.u[1] = f2bf(vb.y); pb.u[2] = f2bf(vb.z); pb.u[3] = f2bf(vb.w);
  ((uint2*)oa)[idx] = pa.v;
  ((uint2*)ob)[idx] = pb.v;
}

// ---------------- unified transpose+cast for all weights ----------------
struct TC { const float* s[6]; };

__global__ __launch_bounds__(256) void tcast_all(TC src, unsigned short* __restrict__ WT4,
                                                 unsigned short* __restrict__ W1T,
                                                 unsigned short* __restrict__ W2T) {
  __shared__ float tile[32][33];
  int z = blockIdx.z;
  const float* Ws; unsigned short* WTs; int K, N, n0, k0;
  if (z < 8) {
    if (blockIdx.x >= 24) return;
    int widx = z >> 1, l = z & 1;
    Ws = src.s[widx] + (size_t)l * DD * DD;
    WTs = WT4 + ((size_t)widx * 2 + l) * DD * DD;
    K = DD; N = DD; n0 = blockIdx.x * 32; k0 = blockIdx.y * 32;
  } else if (z < 10) {
    int l = z - 8;
    Ws = src.s[4] + (size_t)l * DD * FF;
    WTs = W1T + (size_t)l * FF * DD;
    K = DD; N = FF; n0 = blockIdx.x * 32; k0 = blockIdx.y * 32;
  } else {
    int l = z - 10;
    Ws = src.s[5] + (size_t)l * FF * DD;
    WTs = W2T + (size_t)l * DD * FF;
    K = FF; N = DD; n0 = blockIdx.y * 32; k0 = blockIdx.x * 32;
  }
  int tx = threadIdx.x, ty = threadIdx.y;  // (32,8)
  #pragma unroll
  for (int r = 0; r < 4; ++r) tile[ty + 8 * r][tx] = Ws[(size_t)(k0 + ty + 8 * r) * N + (n0 + tx)];
  __syncthreads();
  #pragma unroll
  for (int r = 0; r < 4; ++r) WTs[(size_t)(n0 + ty + 8 * r) * K + (k0 + tx)] = f2bf(tile[tx][ty + 8 * r]);
}

// ---------------- masked max pooling + zero_indic + bit-packed inclusion mask ----------------
__global__ __launch_bounds__(256) void pool_kernel(const float* __restrict__ hs0, const int* __restrict__ mask,
                                                   int* __restrict__ zi, float* __restrict__ qf,
                                                   unsigned short* __restrict__ qb,
                                                   unsigned long long* __restrict__ pmask) {
  __shared__ float eadd[SS];
  int bi = blockIdx.x;  // b*II + i
  int b = bi >> 6, dz = blockIdx.y, t = threadIdx.x, w = t >> 6;
  const int* mrow = mask + (size_t)bi * SS;
  int m0v = mrow[t], m1v = mrow[t + 256];
  eadd[t] = m0v ? -__builtin_inff() : 0.0f;
  eadd[t + 256] = m1v ? -__builtin_inff() : 0.0f;
  int incl = (m0v == 0) | (m1v == 0);
  int any = __syncthreads_or(incl);
  int z = !any;
  if (dz == 0) {
    unsigned long long w0 = __ballot(z || (m0v == 0));
    unsigned long long w1 = __ballot(z || (m1v == 0));
    if ((t & 63) == 0) {
      pmask[bi * 8 + w] = w0;
      pmask[bi * 8 + 4 + w] = w1;
      if (t == 0) zi[bi] = z;
    }
  }
  const float* hb = hs0 + (size_t)b * SS * DD + dz * 256 + t;
  float m[8];
  #pragma unroll
  for (int j = 0; j < 8; ++j) m[j] = -3.4e38f;
  for (int s0 = 0; s0 < SS; s0 += 8) {
    #pragma unroll
    for (int j = 0; j < 8; ++j)
      m[j] = fmaxf(m[j], hb[(size_t)(s0 + j) * DD] + eadd[s0 + j]);
  }
  float mm = fmaxf(fmaxf(fmaxf(m[0], m[1]), fmaxf(m[2], m[3])),
                   fmaxf(fmaxf(m[4], m[5]), fmaxf(m[6], m[7])));
  size_t o = (size_t)bi * DD + dz * 256 + t;
  qf[o] = mm;
  qb[o] = f2bf(mm);
}

// ---------------- NT GEMM 128x128 (4 problems via z; odd z = transposed block map) ----------------
struct GB { const unsigned short* A; const unsigned short* Bt; const float* bias; void* C;
            int M; int N; int rowbias; };

template <int GELU, int OUTBF>
__global__ __launch_bounds__(256) void gemm_nt(GB g0, GB g1, GB g2, GB g3, int K) {
  __shared__ unsigned short Al[128 * 64];
  __shared__ unsigned short Bl[128 * 64];
  GB g = (blockIdx.z == 0) ? g0 : (blockIdx.z == 1) ? g1 : (blockIdx.z == 2) ? g2 : g3;
  int bm = blockIdx.x, bn = blockIdx.y;
  if (blockIdx.z & 1) { bm = blockIdx.y; bn = blockIdx.x; }
  if (bm * 128 >= g.M) return;
  int t = threadIdx.x, w = t >> 6, lane = t & 63;
  int hi = lane >> 4, lo = lane & 15;
  int wr = w >> 1, wc = w & 1;
  f32x4 acc[4][4] = {};
  const char* Abase = (const char*)g.A + (size_t)(bm * 128) * (size_t)K * 2;
  const char* Bbase = (const char*)g.Bt + (size_t)(bn * 128) * (size_t)K * 2;
  int rowbytes = K * 2;
  int KT = K >> 6;
  for (int kt = 0; kt < KT; ++kt) {
    int k0b = kt * 128;
    #pragma unroll
    for (int c = 0; c < 4; ++c) {
      int base = (c * 4 + w) << 10;
      int o = base + lane * 16;
      int row = o >> 7, cb = o & 127;
      int scb = cb ^ ((row & 7) << 4);
      gload_lds16(Abase + (size_t)row * rowbytes + (k0b + scb), (char*)Al + base);
      gload_lds16(Bbase + (size_t)row * rowbytes + (k0b + scb), (char*)Bl + base);
    }
    __syncthreads();
    #pragma unroll
    for (int kk = 0; kk < 2; ++kk) {
      short8 av[4], bv_[4];
      #pragma unroll
      for (int mi = 0; mi < 4; ++mi) {
        int r = wr * 64 + mi * 16 + lo;
        av[mi] = *(const short8*)((const char*)Al + r * 128 + ((kk * 64 + hi * 16) ^ ((r & 7) << 4)));
      }
      #pragma unroll
      for (int ni = 0; ni < 4; ++ni) {
        int r = wc * 64 + ni * 16 + lo;
        bv_[ni] = *(const short8*)((const char*)Bl + r * 128 + ((kk * 64 + hi * 16) ^ ((r & 7) << 4)));
      }
      #pragma unroll
      for (int mi = 0; mi < 4; ++mi)
        #pragma unroll
        for (int ni = 0; ni < 4; ++ni)
          acc[mi][ni] = __builtin_amdgcn_mfma_f32_16x16x32_bf16(av[mi], bv_[ni], acc[mi][ni], 0, 0, 0);
    }
    __syncthreads();
  }
  int mbase = bm * 128 + wr * 64;
  int nbase = bn * 128 + wc * 64;
  #pragma unroll
  for (int mi = 0; mi < 4; ++mi)
    #pragma unroll
    for (int ni = 0; ni < 4; ++ni)
      #pragma unroll
      for (int r = 0; r < 4; ++r) {
        int gm = mbase + mi * 16 + hi * 4 + r;
        int gn = nbase + ni * 16 + lo;
        float v = acc[mi][ni][r] + (g.rowbias ? g.bias[gm] : g.bias[gn]);
        if (GELU) v = 0.5f * v * (1.0f + erff(v * 0.70710678118654752f));
        if (OUTBF) ((unsigned short*)g.C)[(size_t)gm * g.N + gn] = f2bf(v);
        else       ((float*)g.C)[(size_t)gm * g.N + gn] = v;
      }
}

// ---------------- split-K NT GEMM 64x64, double-buffered 2-phase pipeline ----------------
// PARTIAL=1: writes fp32 partial (no bias) to C + z*M*N; else bias(+GELU) epilogue.
template <int GELU, int OUTBF, int PARTIAL>
__global__ __launch_bounds__(256) void gemm_sk(GB g, int K, int kLen) {
  __shared__ unsigned short Al[2][64 * 64];
  __shared__ unsigned short Bl[2][64 * 64];
  int bm = blockIdx.x, bn = blockIdx.y, bz = blockIdx.z;
  int t = threadIdx.x, w = t >> 6, lane = t & 63;
  int hi = lane >> 4, lo = lane & 15;
  int wr = w >> 1, wc = w & 1;
  f32x4 acc[2][2] = {};
  size_t rb = (size_t)K * 2;
  const char* Abase = (const char*)g.A + (size_t)(bm * 64) * rb + (size_t)bz * kLen * 2;
  const char* Bbase = (const char*)g.Bt + (size_t)(bn * 64) * rb + (size_t)bz * kLen * 2;
  int KT = kLen >> 6;
  auto STAGE = [&](int buf, int kt) {
    int k0b = kt * 128;
    #pragma unroll
    for (int c = 0; c < 2; ++c) {
      int base = (c * 4 + w) << 10;
      int o = base + lane * 16;
      int row = o >> 7, cb = o & 127;
      int scb = cb ^ ((row & 7) << 4);
      gload_lds16(Abase + (size_t)row * rb + (k0b + scb), (char*)Al[buf] + base);
      gload_lds16(Bbase + (size_t)row * rb + (k0b + scb), (char*)Bl[buf] + base);
    }
  };
  STAGE(0, 0);
  asm volatile("s_waitcnt vmcnt(0)" ::: "memory");
  __builtin_amdgcn_s_barrier();
  int cur = 0;
  for (int kt = 0; kt < KT; ++kt) {
    if (kt + 1 < KT) STAGE(cur ^ 1, kt + 1);  // overlap next-tile loads with MFMA
    #pragma unroll
    for (int kk = 0; kk < 2; ++kk) {
      short8 av[2], bv_[2];
      #pragma unroll
      for (int mi = 0; mi < 2; ++mi) {
        int r = wr * 32 + mi * 16 + lo;
        av[mi] = *(const short8*)((const char*)Al[cur] + r * 128 + ((kk * 64 + hi * 16) ^ ((r & 7) << 4)));
      }
      #pragma unroll
      for (int ni = 0; ni < 2; ++ni) {
        int r = wc * 32 + ni * 16 + lo;
        bv_[ni] = *(const short8*)((const char*)Bl[cur] + r * 128 + ((kk * 64 + hi * 16) ^ ((r & 7) << 4)));
      }
      #pragma unroll
      for (int mi = 0; mi < 2; ++mi)
        #pragma unroll
        for (int ni = 0; ni < 2; ++ni)
          acc[mi][ni] = __builtin_amdgcn_mfma_f32_16x16x32_bf16(av[mi], bv_[ni], acc[mi][ni], 0, 0, 0);
    }
    if (kt + 1 < KT) {
      asm volatile("s_waitcnt vmcnt(0)" ::: "memory");
      __builtin_amdgcn_s_barrier();
      cur ^= 1;
    }
  }
  int mbase = bm * 64 + wr * 32;
  int nbase = bn * 64 + wc * 32;
  #pragma unroll
  for (int mi = 0; mi < 2; ++mi)
    #pragma unroll
    for (int ni = 0; ni < 2; ++ni)
      #pragma unroll
      for (int r = 0; r < 4; ++r) {
        int gm = mbase + mi * 16 + hi * 4 + r;
        int gn = nbase + ni * 16 + lo;
        if (PARTIAL) {
          ((float*)g.C)[((size_t)bz * g.M + gm) * g.N + gn] = acc[mi][ni][r];
        } else {
          float v = acc[mi][ni][r] + g.bias[gn];
          if (GELU) v = 0.5f * v * (1.0f + erff(v * 0.70710678118654752f));
          if (OUTBF) ((unsigned short*)g.C)[(size_t)gm * g.N + gn] = f2bf(v);
          else       ((float*)g.C)[(size_t)gm * g.N + gn] = v;
        }
      }
}

// ---------------- fused attention per (b,h): Qproj + QK^T + softmax + PV ----------------
#define ATTN_LDS 145664
__global__ __launch_bounds__(256) void attn_kernel(
    const unsigned short* __restrict__ qbuf, const unsigned short* __restrict__ WqTl,
    const float* __restrict__ bql, const unsigned short* __restrict__ khb,
    const unsigned short* __restrict__ vTall, const unsigned long long* __restrict__ pmask,
    unsigned short* __restrict__ ctx) {
  extern __shared__ char lds[];
  char* Qd = lds;
  char* KP = lds + 8192;
  char* Vd = lds + 8192 + 65536;
  unsigned long long* pm = (unsigned long long*)(lds + 139264);
  float* red  = (float*)(lds + 143360);
  float* red2 = (float*)(lds + 144384);
  float* rnv  = (float*)(lds + 145408);
  int bh = blockIdx.x;
  int b = bh / HH, h = bh - b * HH;
  int t = threadIdx.x, w = t >> 6, l = t & 63, hi = l >> 4, lo = l & 15;
  int o16 = l * 16, ro = o16 >> 7, cb = o16 & 127;

  const char* vsrc = (const char*)vTall + (size_t)(h * 64) * 4096 + (size_t)b * 1024;
  #pragma unroll
  for (int rr = 0; rr < 16; ++rr) {
    int rv = w * 16 + rr;
    gload_lds16(vsrc + (size_t)rv * 4096 + ((l * 16) ^ ((rv & 7) << 4)), Vd + rv * 1024);
  }
  if (w == 0) {
    const char* psrc = (const char*)pmask + (size_t)b * 4096;
    #pragma unroll
    for (int c = 0; c < 4; ++c) gload_lds16(psrc + c * 1024 + l * 16, (char*)pm + c * 1024);
  }

  const char* Aq = (const char*)qbuf + (size_t)(b * II) * 1536;
  const char* Bq = (const char*)WqTl + (size_t)(h * 64) * 1536;
  f32x4 qacc[4] = {};
  #pragma unroll
  for (int cc = 0; cc < 2; ++cc) {
    int ch = w * 2 + cc, row = ch * 8 + ro;
    int scb = cb ^ ((row & 7) << 4);
    gload_lds16(Aq + (size_t)row * 1536 + scb, KP + ch * 1024);
    gload_lds16(Bq + (size_t)row * 1536 + scb, KP + 8192 + ch * 1024);
  }
  __syncthreads();
  for (int kt = 0; kt < 12; ++kt) {
    int cur = (kt & 1) * 16384;
    if (kt < 11) {
      int nxt = ((kt + 1) & 1) * 16384;
      int kb = (kt + 1) * 128;
      #pragma unroll
      for (int cc = 0; cc < 2; ++cc) {
        int ch = w * 2 + cc, row = ch * 8 + ro;
        int scb = kb + (cb ^ ((row & 7) << 4));
        gload_lds16(Aq + (size_t)row * 1536 + scb, KP + nxt + ch * 1024);
        gload_lds16(Bq + (size_t)row * 1536 + scb, KP + nxt + 8192 + ch * 1024);
      }
    }
    #pragma unroll
    for (int kk = 0; kk < 2; ++kk) {
      int ra = w * 16 + lo;
      short8 av = *(const short8*)(KP + cur + ra * 128 + ((kk * 64 + hi * 16) ^ ((ra & 7) << 4)));
      #pragma unroll
      for (int ni = 0; ni < 4; ++ni) {
        int rb2 = ni * 16 + lo;
        short8 bv = *(const short8*)(KP + cur + 8192 + rb2 * 128 + ((kk * 64 + hi * 16) ^ ((rb2 & 7) << 4)));
        qacc[ni] = __builtin_amdgcn_mfma_f32_16x16x32_bf16(av, bv, qacc[ni], 0, 0, 0);
      }
    }
    __syncthreads();
  }
  #pragma unroll
  for (int ni = 0; ni < 4; ++ni)
    #pragma unroll
    for (int r = 0; r < 4; ++r) {
      int row = w * 16 + hi * 4 + r, col = ni * 16 + lo;
      float v = qacc[ni][r] + bql[h * 64 + col];
      *(unsigned short*)(Qd + row * 128 + ((col * 2) ^ ((row & 7) << 4))) = f2bf(v);
    }
  const char* Ks = (const char*)khb + (size_t)(b * SS) * 1536 + h * 128;
  #pragma unroll
  for (int cc = 0; cc < 16; ++cc) {
    int ch = w * 16 + cc, row = ch * 8 + ro;
    int scb = cb ^ ((row & 7) << 4);
    gload_lds16(Ks + (size_t)row * 1536 + scb, KP + ch * 1024);
  }
  __syncthreads();

  f32x4 acc[4][8] = {};
  #pragma unroll
  for (int kk = 0; kk < 2; ++kk) {
    short8 av[4];
    #pragma unroll
    for (int mi = 0; mi < 4; ++mi) {
      int ra = mi * 16 + lo;
      av[mi] = *(const short8*)(Qd + ra * 128 + ((kk * 64 + hi * 16) ^ ((ra & 7) << 4)));
    }
    #pragma unroll
    for (int ni = 0; ni < 8; ++ni) {
      int rk = w * 128 + ni * 16 + lo;
      short8 bv = *(const short8*)(KP + rk * 128 + ((kk * 64 + hi * 16) ^ ((rk & 7) << 4)));
      #pragma unroll
      for (int mi = 0; mi < 4; ++mi)
        acc[mi][ni] = __builtin_amdgcn_mfma_f32_16x16x32_bf16(av[mi], bv, acc[mi][ni], 0, 0, 0);
    }
  }
  #pragma unroll
  for (int mi = 0; mi < 4; ++mi)
    #pragma unroll
    for (int r = 0; r < 4; ++r) {
      float m = acc[mi][0][r];
      #pragma unroll
      for (int ni = 1; ni < 8; ++ni) m = fmaxf(m, acc[mi][ni][r]);
      #pragma unroll
      for (int xm = 1; xm <= 8; xm <<= 1) m = fmaxf(m, __shfl_xor(m, xm));
      if (lo == 0) red[(mi * 16 + hi * 4 + r) * 4 + w] = m;
    }
  __syncthreads();
  #pragma unroll
  for (int mi = 0; mi < 4; ++mi)
    #pragma unroll
    for (int r = 0; r < 4; ++r) {
      int row = mi * 16 + hi * 4 + r;
      float4 rm4 = *(const float4*)&red[row * 4];
      float gm = fmaxf(fmaxf(rm4.x, rm4.y), fmaxf(rm4.z, rm4.w));
      unsigned long long w0 = pm[row * 8 + w * 2 + 0];
      unsigned long long w1 = pm[row * 8 + w * 2 + 1];
      float s = 0.f;
      #pragma unroll
      for (int ni = 0; ni < 8; ++ni) {
        int sl = ni * 16 + lo;
        unsigned long long word = (sl < 64) ? w0 : w1;
        float in = ((word >> (sl & 63)) & 1ull) ? 1.0f : 0.0f;
        float e = __expf((acc[mi][ni][r] - gm) * 0.125f) * in;
        s += e;
        int sbyte = w * 256 + ni * 32 + lo * 2;
        *(unsigned short*)(KP + row * 1024 + (sbyte ^ ((row & 7) << 4))) = f2bf(e);
      }
      #pragma unroll
      for (int xm = 1; xm <= 8; xm <<= 1) s += __shfl_xor(s, xm);
      if (lo == 0) red2[row * 4 + w] = s;
    }
  __syncthreads();
  if (w == 0 && lo == 0) {
    #pragma unroll
    for (int mi = 0; mi < 4; ++mi)
      #pragma unroll
      for (int r = 0; r < 4; ++r) {
        int row = mi * 16 + hi * 4 + r;
        float4 s4 = *(const float4*)&red2[row * 4];
        rnv[row] = 1.0f / ((s4.x + s4.y) + (s4.z + s4.w));
      }
  }
  __syncthreads();
  f32x4 pacc[4] = {};
  for (int kk = 0; kk < 16; ++kk) {
    int rv = w * 16 + lo;
    short8 bv = *(const short8*)(Vd + rv * 1024 + ((kk * 64 + hi * 16) ^ ((rv & 7) << 4)));
    #pragma unroll
    for (int mi = 0; mi < 4; ++mi) {
      int ra = mi * 16 + lo;
      short8 av = *(const short8*)(KP + ra * 1024 + ((kk * 64 + hi * 16) ^ ((ra & 7) << 4)));
      pacc[mi] = __builtin_amdgcn_mfma_f32_16x16x32_bf16(av, bv, pacc[mi], 0, 0, 0);
    }
  }
  #pragma unroll
  for (int mi = 0; mi < 4; ++mi)
    #pragma unroll
    for (int r = 0; r < 4; ++r) {
      int row = mi * 16 + hi * 4 + r;
      ctx[(size_t)(b * II + row) * DD + h * 64 + w * 16 + lo] = f2bf(pacc[mi][r] * rnv[row]);
    }
}

// ---------------- residual + Σ(NP split-K partials) + gemm-bias + LayerNorm ----------------
// FINAL=1 fuses zero-context substitution into d_out.
template <int FINAL, int NP>
__global__ __launch_bounds__(256) void ln_kernel(const float* __restrict__ x, const float* __restrict__ y,
                                                 const float* __restrict__ gb,
                                                 const float* __restrict__ g, const float* __restrict__ bb,
                                                 float* __restrict__ qf, unsigned short* __restrict__ qb,
                                                 const int* __restrict__ zi, const float* __restrict__ zc,
                                                 float* __restrict__ out) {
  __shared__ float r1[4], r2[4];
  const int MN = BB * II * DD;
  int r = blockIdx.x, t = threadIdx.x;
  size_t o = (size_t)r * DD;
  float v0 = x[o + t] + gb[t];
  float v1 = x[o + t + 256] + gb[t + 256];
  float v2 = x[o + t + 512] + gb[t + 512];
  #pragma unroll
  for (int p = 0; p < NP; ++p) {
    size_t po = (size_t)p * MN + o;
    v0 += y[po + t];
    v1 += y[po + t + 256];
    v2 += y[po + t + 512];
  }
  float s = v0 + v1 + v2, ss = v0 * v0 + v1 * v1 + v2 * v2;
  #pragma unroll
  for (int o2 = 32; o2; o2 >>= 1) { s += __shfl_xor(s, o2); ss += __shfl_xor(ss, o2); }
  if ((t & 63) == 0) { r1[t >> 6] = s; r2[t >> 6] = ss; }
  __syncthreads();
  s = r1[0] + r1[1] + r1[2] + r1[3];
  ss = r2[0] + r2[1] + r2[2] + r2[3];
  float mean = s * (1.0f / DD);
  float var = ss * (1.0f / DD) - mean * mean;
  float inv = rsqrtf(var + 1e-12f);
  float w0 = (v0 - mean) * inv * g[t] + bb[t];
  float w1 = (v1 - mean) * inv * g[t + 256] + bb[t + 256];
  float w2 = (v2 - mean) * inv * g[t + 512] + bb[t + 512];
  if (FINAL) {
    int z = zi[r];
    out[o + t] = z ? zc[t] : w0;
    out[o + t + 256] = z ? zc[t + 256] : w1;
    out[o + t + 512] = z ? zc[t + 512] : w2;
  } else {
    qf[o + t] = w0; qf[o + t + 256] = w1; qf[o + t + 512] = w2;
    qb[o + t] = f2bf(w0); qb[o + t + 256] = f2bf(w1); qb[o + t + 512] = f2bf(w2);
  }
}

extern "C" void kernel_launch(void* const* d_in, const int* in_sizes, int n_in,
                              void* d_out, int out_size, void* d_ws, size_t ws_size,
                              hipStream_t stream) {
  (void)in_sizes; (void)n_in; (void)out_size; (void)ws_size;
  const float* hs0 = (const float*)d_in[0];
  const float* hs1 = (const float*)d_in[1];
  const float* Wq  = (const float*)d_in[3];
  const float* bq  = (const float*)d_in[4];
  const float* Wk  = (const float*)d_in[5];
  const float* bk  = (const float*)d_in[6];
  const float* Wv  = (const float*)d_in[7];
  const float* bv  = (const float*)d_in[8];
  const float* Wo  = (const float*)d_in[9];
  const float* bo  = (const float*)d_in[10];
  const float* ln1g = (const float*)d_in[11];
  const float* ln1b = (const float*)d_in[12];
  const float* W1  = (const float*)d_in[13];
  const float* b1  = (const float*)d_in[14];
  const float* W2  = (const float*)d_in[15];
  const float* b2  = (const float*)d_in[16];
  const float* ln2g = (const float*)d_in[17];
  const float* ln2b = (const float*)d_in[18];
  const float* zc  = (const float*)d_in[19];
  const int*   mask = (const int*)d_in[20];

  char* ws = (char*)d_ws;
  size_t off = 0;
  auto alloc = [&](size_t bytes) { size_t o = off; off += (bytes + 255) & ~(size_t)255; return o; };

  unsigned short* WT4 = (unsigned short*)(ws + alloc((size_t)4 * LL * DD * DD * 2));
  unsigned short* W1T = (unsigned short*)(ws + alloc((size_t)LL * FF * DD * 2));
  unsigned short* W2T = (unsigned short*)(ws + alloc((size_t)LL * DD * FF * 2));
  unsigned short* hsb = (unsigned short*)(ws + alloc((size_t)2 * BB * SS * DD * 2));
  float*          qf  = (float*)(ws + alloc((size_t)BB * II * DD * 4));
  unsigned short* qb  = (unsigned short*)(ws + alloc((size_t)BB * II * DD * 2));
  unsigned short* khb = (unsigned short*)(ws + alloc((size_t)LL * BB * SS * DD * 2));
  unsigned short* vTall = (unsigned short*)(ws + alloc((size_t)LL * DD * BB * SS * 2));
  unsigned short* ctxb = (unsigned short*)(ws + alloc((size_t)BB * II * DD * 2));
  float*          att_o = (float*)(ws + alloc((size_t)2 * BB * II * DD * 4));   // 2 split-K partials
  unsigned short* ffh = (unsigned short*)(ws + alloc((size_t)BB * II * FF * 2));
  float*          ffo = (float*)(ws + alloc((size_t)4 * BB * II * DD * 4));     // 4 split-K partials
  unsigned long long* pmask = (unsigned long long*)(ws + alloc((size_t)BB * II * 8 * 8));
  int*            zib = (int*)(ws + alloc((size_t)BB * II * 4));

  unsigned short* WqT = WT4 + 0 * (size_t)LL * DD * DD;
  unsigned short* WkT = WT4 + 1 * (size_t)LL * DD * DD;
  unsigned short* WvT = WT4 + 2 * (size_t)LL * DD * DD;
  unsigned short* WoT = WT4 + 3 * (size_t)LL * DD * DD;

  (void)hipFuncSetAttribute((const void*)attn_kernel,
                            hipFuncAttributeMaxDynamicSharedMemorySize, ATTN_LDS);

  dim3 tb(32, 8);
  TC tc = { { Wq, Wk, Wv, Wo, W1, W2 } };
  tcast_all<<<dim3(96, 24, 12), tb, 0, stream>>>(tc, WT4, W1T, W2T);
  cast2_kernel<<<(BB * SS * DD / 4) / 256, 256, 0, stream>>>(hs0, hs1, hsb, hsb + (size_t)BB * SS * DD);
  pool_kernel<<<dim3(BB * II, 3), 256, 0, stream>>>(hs0, mask, zib, qf, qb, pmask);

  // K projections + transposed V projections for BOTH layers in one launch
  {
    const unsigned short* h0 = hsb;
    const unsigned short* h1 = hsb + (size_t)BB * SS * DD;
    GB gK0 = { h0, WkT, bk, khb, BB * SS, DD, 0 };
    GB gV0 = { WvT, h0, bv, vTall, DD, BB * SS, 1 };
    GB gK1 = { h1, WkT + (size_t)DD * DD, bk + DD, khb + (size_t)BB * SS * DD, BB * SS, DD, 0 };
    GB gV1 = { WvT + (size_t)DD * DD, h1, bv + DD, vTall + (size_t)DD * BB * SS, DD, BB * SS, 1 };
    gemm_nt<0, 1><<<dim3(16, 6, 4), 256, 0, stream>>>(gK0, gV0, gK1, gV1, DD);
  }

  for (int l = 0; l < LL; ++l) {
    const unsigned short* khl = khb + (size_t)l * BB * SS * DD;
    const unsigned short* vTl = vTall + (size_t)l * DD * BB * SS;
    // fused attention (includes Q projection)
    attn_kernel<<<dim3(BB * HH), 256, ATTN_LDS, stream>>>(
        qb, WqT + (size_t)l * DD * DD, bq + l * DD, khl, vTl, pmask, ctxb);
    // Wo projection: split-K=2, fp32 partials
    GB gO = { ctxb, WoT + (size_t)l * DD * DD, nullptr, att_o, BB * II, DD, 0 };
    gemm_sk<0, 0, 1><<<dim3(4, 12, 2), 256, 0, stream>>>(gO, DD, DD / 2);
    // LN1: residual + 2 partials + bo
    ln_kernel<0, 2><<<BB * II, 256, 0, stream>>>(qf, att_o, bo + l * DD,
                                                 ln1g + l * DD, ln1b + l * DD, qf, qb,
                                                 nullptr, nullptr, nullptr);
    // FFN1 (GELU, bf16 out), K=768, 192 blocks
    GB gF1 = { qb, W1T + (size_t)l * FF * DD, b1 + l * FF, ffh, BB * II, FF, 0 };
    gemm_sk<1, 1, 0><<<dim3(4, FF / 64, 1), 256, 0, stream>>>(gF1, DD, DD);
    // FFN2: split-K=4, fp32 partials
    GB gF2 = { ffh, W2T + (size_t)l * DD * FF, nullptr, ffo, BB * II, DD, 0 };
    gemm_sk<0, 0, 1><<<dim3(4, 12, 4), 256, 0, stream>>>(gF2, FF, FF / 4);
    // LN2: residual + 4 partials + b2 (layer 1: fused zero-context substitution)
    if (l == 0)
      ln_kernel<0, 4><<<BB * II, 256, 0, stream>>>(qf, ffo, b2 + l * DD,
                                                   ln2g + l * DD, ln2b + l * DD, qf, qb,
                                                   nullptr, nullptr, nullptr);
    else
      ln_kernel<1, 4><<<BB * II, 256, 0, stream>>>(qf, ffo, b2 + l * DD,
                                                   ln2g + l * DD, ln2b + l * DD, nullptr, nullptr,
                                                   zib, zc, (float*)d_out);
  }
}